// Round 9
// baseline (92.891 us; speedup 1.0000x reference)
//
#include <hip/hip_runtime.h>
#include <hip/hip_fp16.h>

// ApproxConv2d via 256x256 LUT (approximate multiplier).
// out[b,o,y,x] = sum_{c,ky,kx} lut[ qx(b,c,y+ky-1,x+kx-1)*256 + qw(o,c,ky,kx) ] + bias[o]
// qx/qw = clip(rint(v*64), -128, 127) + 128; padding -> qx=128 -> lut row 128 = 0.
//
// v9: RESIDENT-T blocks. Block = (o-quad, channel-group-of-4, image-half).
// The 4 channels' o-quad tap table (73.7KB) is staged into LDS ONCE and stays
// resident; the block loops over 8 batches with only tiny plane swaps
// (2 barriers/batch). This removes v8's per-iteration 36.9KB staging whose
// unhidden L2 latency was ~30% of runtime (v8: VALUBusy 23%, occ 19.7%).
// Gather inner loop = v8's proven o-quad b64 pattern (1 ds_read_b64 = 4 MACs
// via 2 __hadd2; conflicts measured 7.4e6). Cross-group reduction by f32 HW
// atomics into a bias-initialized out (8.4M adds ~ few us).

#define NT 256

__device__ __forceinline__ int quantize(float v) {
    // clip(rint(v*64), -128, 127) + 128; rintf = round-half-to-even = jnp.round
    int q = (int)rintf(v * 64.0f);
    q = q < -128 ? -128 : q;
    q = q > 127 ? 127 : q;
    return q + 128;
}

__device__ __forceinline__ void gll16(const void* g, void* l) {
    __builtin_amdgcn_global_load_lds(
        (const __attribute__((address_space(1))) unsigned int*)g,
        (__attribute__((address_space(3))) unsigned int*)l, 16, 0, 0);
}

// -------- bias init: out[b][o][*] = bias[o]; 512 blocks x 256 x float4 ------
__global__ __launch_bounds__(NT, 4)
void bias_init(const float* __restrict__ bias, float* __restrict__ out)
{
    int v = blockIdx.x * NT + threadIdx.x;      // float4 index, 131072 total
    float bo = bias[(v >> 8) & 63];             // 256 float4 per (b,o) image
    ((float4*)out)[v] = make_float4(bo, bo, bo, bo);
}

// -------- build: T[quad][c][ky][qx] 24B o-quad rows (v8-proven layout) ------
__global__ __launch_bounds__(NT, 2)
void build_T4(const float* __restrict__ w, const float* __restrict__ lut,
              unsigned int* __restrict__ T)
{
    __shared__ float band[8 * 257];          // 8 lut rows, +1 pad
    __shared__ unsigned char qw4[4][576];

    const int tid = threadIdx.x;
    const int quad = blockIdx.x >> 5;        // 0..15
    const int q0 = (blockIdx.x & 31) << 3;   // qx slice base (8 rows)

    for (int i = tid; i < 4 * 576; i += NT) {
        int oo = i / 576, idx = i - oo * 576;
        qw4[oo][idx] = (unsigned char)quantize(w[(quad * 4 + oo) * 576 + idx]);
    }
    for (int i = tid; i < 8 * 256; i += NT) {
        int r = i >> 8, c2 = i & 255;
        band[r * 257 + c2] = lut[(q0 + r) * 256 + c2];
    }
    __syncthreads();

    // 64c x 3ky x 8qx = 1536 items; each writes one 24B row (3x uint2)
    for (int it = 0; it < 6; ++it) {
        int idx = it * NT + tid;
        int c = idx / 24;
        int rem = idx - c * 24;
        int ky = rem >> 3;
        int qxl = rem & 7;
        const float* brow = band + qxl * 257;
        const int wb = c * 9 + ky * 3;
        unsigned int* dst =
            T + (((size_t)(quad * 64 + c) * 3 + ky) * 256 + q0 + qxl) * 6;
        #pragma unroll
        for (int k = 0; k < 3; ++k) {
            unsigned int h0 = __half_as_ushort(__float2half(brow[qw4[0][wb + k]]));
            unsigned int h1 = __half_as_ushort(__float2half(brow[qw4[1][wb + k]]));
            unsigned int h2 = __half_as_ushort(__float2half(brow[qw4[2][wb + k]]));
            unsigned int h3 = __half_as_ushort(__float2half(brow[qw4[3][wb + k]]));
            *(uint2*)(dst + k * 2) = make_uint2(h0 | (h1 << 16), h2 | (h3 << 16));
        }
    }
}

// -------- main: block = (quad, cgroup4, half); T resident; loop batches -----
__global__ __launch_bounds__(NT, 2)
void approx_res(const float* __restrict__ x, const unsigned int* __restrict__ T,
                float* __restrict__ out)
{
    __shared__ __align__(16) unsigned char Tq[73728];   // 4 channels' tables
    __shared__ __align__(8) unsigned char planes[4][720]; // 18 rows x 40B each

    const int tid = threadIdx.x;
    const int bid = blockIdx.x;
    const int quad = bid & 15;               // XCD = bid%8 -> 2 quads' T per L2
    const int g2 = bid >> 4;                 // 0..31
    const int cg = g2 & 15;                  // channel group
    const int h = g2 >> 4;                   // image half (rows 0-15 / 16-31)
    const int c0 = cg * 4;
    const int o0 = quad * 4;

    const int yl = tid >> 4;                 // local row 0..15
    const int x0 = (tid & 15) << 1;          // 2-px strip base col
    const int yg = h * 16 + yl;

    // stage 4 channels' T once: 73728B = 18 x 4096B passes
    {
        const char* Tg = (const char*)T + (size_t)(quad * 64 + c0) * 18432;
        #pragma unroll
        for (int p2 = 0; p2 < 18; ++p2)
            gll16(Tg + p2 * 4096 + tid * 16, (char*)Tq + p2 * 4096 + tid * 16);
    }
    // plane init: all 4 planes to q=128 (invalid halos/sides persist)
    for (int i = tid; i < 720; i += NT) ((unsigned int*)planes)[i] = 0x80808080u;

    // halo duty: each thread owns one (channel, halo-row, col) byte
    const int hc = tid >> 6;                 // halo channel 0..3
    const int hr = (tid >> 5) & 1;           // 0 top, 1 bottom
    const int hcol = tid & 31;
    const int hgrow = h * 16 + (hr ? 16 : -1);
    const int hvalid = (hgrow >= 0 && hgrow < 32);
    const int hpr = hr ? 17 : 0;

    // prefetch b=0 pixels (4 channels x float2) + halo
    float2 xv[4];
    float xh = 0.f;
    {
        const float* xb = x;                 // b = 0
        #pragma unroll
        for (int c = 0; c < 4; ++c)
            xv[c] = *(const float2*)(xb + (size_t)(c0 + c) * 1024 + yg * 32 + x0);
        if (hvalid) xh = xb[(size_t)(c0 + hc) * 1024 + hgrow * 32 + hcol];
    }

    __syncthreads();   // plane init + T staging (vmcnt drain) complete

    float a32[2][4];
    #pragma unroll
    for (int px = 0; px < 2; ++px)
        #pragma unroll
        for (int oo = 0; oo < 4; ++oo) a32[px][oo] = 0.f;

    for (int b = 0; b < 8; ++b) {
        // write planes from prefetched regs
        #pragma unroll
        for (int c = 0; c < 4; ++c) {
            int qa = quantize(xv[c].x), qb = quantize(xv[c].y);
            *(unsigned short*)(&planes[c][(yl + 1) * 40 + 4 + x0]) =
                (unsigned short)(qa | (qb << 8));
        }
        if (hvalid) planes[hc][hpr * 40 + 4 + hcol] = (unsigned char)quantize(xh);
        __syncthreads();   // planes visible

        // prefetch b+1 (clamped; discarded on last iter)
        {
            const int bn = b < 7 ? b + 1 : 7;
            const float* xb = x + (size_t)bn * 65536;
            #pragma unroll
            for (int c = 0; c < 4; ++c)
                xv[c] = *(const float2*)(xb + (size_t)(c0 + c) * 1024 + yg * 32 + x0);
            if (hvalid) xh = xb[(size_t)(c0 + hc) * 1024 + hgrow * 32 + hcol];
        }

        // compute 4 channels from resident T
        __half2 z2 = __float2half2_rn(0.f);
        __half2 ah00 = z2, ah01 = z2, ah10 = z2, ah11 = z2;  // [px][o-pair]
        #pragma unroll
        for (int c = 0; c < 4; ++c) {
            const unsigned int* pl = (const unsigned int*)planes[c];
            const char* Tc = (const char*)Tq + c * 18432;
            #pragma unroll
            for (int ky = 0; ky < 3; ++ky) {
                const int pbase = (yl + ky) * 10;
                const int j0 = (x0 + 3) >> 2;
                unsigned int wlo = pl[pbase + j0];
                unsigned int whi = pl[pbase + j0 + 1];
                unsigned long long dv = ((unsigned long long)whi << 32) | wlo;
                unsigned int qbts = (unsigned int)(dv >> (((x0 + 3) & 3) * 8));
                int m0 = (int)(qbts & 255u), m1 = (int)((qbts >> 8) & 255u);
                int m2 = (int)((qbts >> 16) & 255u), m3 = (int)(qbts >> 24);
                const char* Tk = Tc + ky * 6144;
                uint2 A = *(const uint2*)(Tk + m0 * 24);       // px0 k0
                uint2 Bv = *(const uint2*)(Tk + m1 * 24 + 8);  // px0 k1
                uint2 Cv = *(const uint2*)(Tk + m2 * 24 + 16); // px0 k2
                uint2 D = *(const uint2*)(Tk + m1 * 24);       // px1 k0
                uint2 E = *(const uint2*)(Tk + m2 * 24 + 8);   // px1 k1
                uint2 F = *(const uint2*)(Tk + m3 * 24 + 16);  // px1 k2
                ah00 = __hadd2(ah00, *(__half2*)&A.x);  ah01 = __hadd2(ah01, *(__half2*)&A.y);
                ah00 = __hadd2(ah00, *(__half2*)&Bv.x); ah01 = __hadd2(ah01, *(__half2*)&Bv.y);
                ah00 = __hadd2(ah00, *(__half2*)&Cv.x); ah01 = __hadd2(ah01, *(__half2*)&Cv.y);
                ah10 = __hadd2(ah10, *(__half2*)&D.x);  ah11 = __hadd2(ah11, *(__half2*)&D.y);
                ah10 = __hadd2(ah10, *(__half2*)&E.x);  ah11 = __hadd2(ah11, *(__half2*)&E.y);
                ah10 = __hadd2(ah10, *(__half2*)&F.x);  ah11 = __hadd2(ah11, *(__half2*)&F.y);
            }
            if (c & 1) {   // migrate fp16 partials to f32 every 2 channels
                a32[0][0] += __low2float(ah00); a32[0][1] += __high2float(ah00);
                a32[0][2] += __low2float(ah01); a32[0][3] += __high2float(ah01);
                a32[1][0] += __low2float(ah10); a32[1][1] += __high2float(ah10);
                a32[1][2] += __low2float(ah11); a32[1][3] += __high2float(ah11);
                ah00 = z2; ah01 = z2; ah10 = z2; ah11 = z2;
            }
        }

        // reduce this batch's partial into out (bias pre-initialized)
        #pragma unroll
        for (int oo = 0; oo < 4; ++oo) {
            float* p = out + ((size_t)(b * 64 + o0 + oo)) * 1024 + yg * 32 + x0;
            unsafeAtomicAdd(p,     a32[0][oo]);
            unsafeAtomicAdd(p + 1, a32[1][oo]);
            a32[0][oo] = 0.f; a32[1][oo] = 0.f;
        }
        __syncthreads();   // all plane reads done before next batch overwrites
    }
}

// -------- fallback (proven v1, 98us): used if ws too small ------------------
#define BW1 61
__global__ __launch_bounds__(NT, 2)
void approxconv2d_v1(const float* __restrict__ x,
                     const float* __restrict__ w,
                     const float* __restrict__ bias,
                     const float* __restrict__ lut,
                     float* __restrict__ out)
{
    __shared__ float band[256 * BW1];
    __shared__ unsigned int plane[340];
    __shared__ unsigned char qwrow[576];
    __shared__ int s_min;

    const int tid = threadIdx.x;
    const int bid = blockIdx.x;
    const int b = bid >> 6;
    const int o = bid & 63;

    if (tid == 0) s_min = 255;
    for (int i = tid; i < 340; i += NT) plane[i] = 0x80808080u;
    __syncthreads();

    int lmin = 255;
    for (int i = tid; i < 576; i += NT) {
        int q = quantize(w[o * 576 + i]);
        qwrow[i] = (unsigned char)q;
        lmin = lmin < q ? lmin : q;
    }
    atomicMin(&s_min, lmin);
    __syncthreads();

    int cmin = s_min;
    if (cmin > 256 - BW1) cmin = 256 - BW1;

    for (int i = tid; i < 256 * BW1; i += NT) {
        int qx = i / BW1;
        int cc = i - qx * BW1;
        band[i] = lut[(qx << 8) + cmin + cc];
    }

    const int y  = tid >> 3;
    const int xq = tid & 7;
    const int x0 = xq << 2;

    float acc0 = 0.f, acc1 = 0.f, acc2 = 0.f, acc3 = 0.f;
    const float* xb = x + (size_t)b * 64 * 1024;
    unsigned char* pb = (unsigned char*)plane;

    for (int c = 0; c < 64; ++c) {
        __syncthreads();
        float4 xv = *(const float4*)(xb + c * 1024 + y * 32 + x0);
        int qa = quantize(xv.x), qb = quantize(xv.y);
        int qc = quantize(xv.z), qd = quantize(xv.w);
        int wbase = (y + 1) * 40 + x0 + 1;
        pb[wbase + 0] = (unsigned char)qa;
        pb[wbase + 1] = (unsigned char)qb;
        pb[wbase + 2] = (unsigned char)qc;
        pb[wbase + 3] = (unsigned char)qd;
        __syncthreads();

        const unsigned char* qwp = qwrow + c * 9;
        #pragma unroll
        for (int ky = 0; ky < 3; ++ky) {
            int ro = (y + ky) * 10 + xq;
            unsigned int r0 = plane[ro];
            unsigned int r1 = plane[ro + 1];
            int ee[6];
            ee[0] = (int)(r0 & 255u);
            ee[1] = (int)((r0 >> 8) & 255u);
            ee[2] = (int)((r0 >> 16) & 255u);
            ee[3] = (int)(r0 >> 24);
            ee[4] = (int)(r1 & 255u);
            ee[5] = (int)((r1 >> 8) & 255u);
            int pp[6];
            #pragma unroll
            for (int tt = 0; tt < 6; ++tt) pp[tt] = ee[tt] * BW1;
            #pragma unroll
            for (int kx = 0; kx < 3; ++kx) {
                int cq = (int)qwp[ky * 3 + kx];
                int cc = cq - cmin;
                if ((unsigned)cc < (unsigned)BW1) {
                    acc0 += band[pp[kx + 0] + cc];
                    acc1 += band[pp[kx + 1] + cc];
                    acc2 += band[pp[kx + 2] + cc];
                    acc3 += band[pp[kx + 3] + cc];
                } else {
                    acc0 += lut[(ee[kx + 0] << 8) + cq];
                    acc1 += lut[(ee[kx + 1] << 8) + cq];
                    acc2 += lut[(ee[kx + 2] << 8) + cq];
                    acc3 += lut[(ee[kx + 3] << 8) + cq];
                }
            }
        }
    }

    float bo = bias[o];
    float4 r;
    r.x = acc0 + bo; r.y = acc1 + bo; r.z = acc2 + bo; r.w = acc3 + bo;
    *(float4*)(out + (size_t)bid * 1024 + y * 32 + x0) = r;
}

extern "C" void kernel_launch(void* const* d_in, const int* in_sizes, int n_in,
                              void* d_out, int out_size, void* d_ws, size_t ws_size,
                              hipStream_t stream) {
    const float* x    = (const float*)d_in[0];
    const float* wgt  = (const float*)d_in[1];
    const float* bias = (const float*)d_in[2];
    const float* lut  = (const float*)d_in[3];
    float* out = (float*)d_out;

    const size_t T_BYTES = (size_t)16 * 64 * 3 * 256 * 24;   // 18,874,368
    if (ws_size >= T_BYTES) {
        hipLaunchKernelGGL(bias_init, dim3(512), dim3(NT), 0, stream, bias, out);
        hipLaunchKernelGGL(build_T4, dim3(512), dim3(NT), 0, stream,
                           wgt, lut, (unsigned int*)d_ws);
        hipLaunchKernelGGL(approx_res, dim3(512), dim3(NT), 0, stream,
                           x, (const unsigned int*)d_ws, out);
    } else {
        hipLaunchKernelGGL(approxconv2d_v1, dim3(512), dim3(NT), 0, stream,
                           x, wgt, bias, lut, out);
    }
}

// Round 10
// 55.556 us; speedup vs baseline: 1.6720x; 1.6720x over previous
//
#include <hip/hip_runtime.h>
#include <hip/hip_fp16.h>

// ApproxConv2d via 256x256 LUT (approximate multiplier).
// out[b,o,y,x] = sum_{c,ky,kx} lut[ qx(b,c,y+ky-1,x+kx-1)*256 + qw(o,c,ky,kx) ] + bias[o]
// qx/qw = clip(rint(v*64), -128, 127) + 128; padding -> qx=128 -> lut row 128 = 0.
//
// v10 = v8 (o-QUAD b64 tap rows, proven) + counted-vmcnt double-buffered
// staging (T3/T4). v8's measured deficit was ~14us of exposed staging latency:
// __syncthreads drains vmcnt(0) every iter. Here Ts is double-buffered and
// each iter issues EXACTLY 11 VMEM ops per thread (1 pixel float2 + 1 clamped
// halo dword + 9 global_load_lds), then waits vmcnt(11) -- tile t's loads are
// retired, tile t+1's 11 stay in flight across a raw s_barrier. Second
// barrier (lgkm only) fences compute-t reads vs next iteration's LDS writes.
// v9's cross-XCD atomic reduction (WRITE_SIZE 67MB, VALUBusy 10%) is dropped;
// v8's in-block parity reduce + direct store returns.

#define NT 256

__device__ __forceinline__ int quantize(float v) {
    // clip(rint(v*64), -128, 127) + 128; rintf = round-half-to-even = jnp.round
    int q = (int)rintf(v * 64.0f);
    q = q < -128 ? -128 : q;
    q = q > 127 ? 127 : q;
    return q + 128;
}

__device__ __forceinline__ void gll16(const void* g, void* l) {
    __builtin_amdgcn_global_load_lds(
        (const __attribute__((address_space(1))) unsigned int*)g,
        (__attribute__((address_space(3))) unsigned int*)l, 16, 0, 0);
}

// -------- build: T[quad][c][ky][qx] 24B o-quad rows (v8-proven) -------------
__global__ __launch_bounds__(NT, 2)
void build_T4(const float* __restrict__ w, const float* __restrict__ lut,
              unsigned int* __restrict__ T)
{
    __shared__ float band[8 * 257];          // 8 lut rows, +1 pad
    __shared__ unsigned char qw4[4][576];

    const int tid = threadIdx.x;
    const int quad = blockIdx.x >> 5;        // 0..15
    const int q0 = (blockIdx.x & 31) << 3;   // qx slice base (8 rows)

    for (int i = tid; i < 4 * 576; i += NT) {
        int oo = i / 576, idx = i - oo * 576;
        qw4[oo][idx] = (unsigned char)quantize(w[(quad * 4 + oo) * 576 + idx]);
    }
    for (int i = tid; i < 8 * 256; i += NT) {
        int r = i >> 8, c2 = i & 255;
        band[r * 257 + c2] = lut[(q0 + r) * 256 + c2];
    }
    __syncthreads();

    // 64c x 3ky x 8qx = 1536 items; each writes one 24B row (3x uint2)
    for (int it = 0; it < 6; ++it) {
        int idx = it * NT + tid;
        int c = idx / 24;
        int rem = idx - c * 24;
        int ky = rem >> 3;
        int qxl = rem & 7;
        const float* brow = band + qxl * 257;
        const int wb = c * 9 + ky * 3;
        unsigned int* dst =
            T + (((size_t)(quad * 64 + c) * 3 + ky) * 256 + q0 + qxl) * 6;
        #pragma unroll
        for (int k = 0; k < 3; ++k) {
            unsigned int h0 = __half_as_ushort(__float2half(brow[qw4[0][wb + k]]));
            unsigned int h1 = __half_as_ushort(__float2half(brow[qw4[1][wb + k]]));
            unsigned int h2 = __half_as_ushort(__float2half(brow[qw4[2][wb + k]]));
            unsigned int h3 = __half_as_ushort(__float2half(brow[qw4[3][wb + k]]));
            *(uint2*)(dst + k * 2) = make_uint2(h0 | (h1 << 16), h2 | (h3 << 16));
        }
    }
}

// -------- main: v8 geometry + dbuf Ts + counted-vmcnt barriers --------------
__global__ __launch_bounds__(NT, 2)
void approx_main(const float* __restrict__ x, const unsigned int* __restrict__ T,
                 const float* __restrict__ bias, float* __restrict__ out)
{
    __shared__ __align__(16) unsigned char Ts[2][36864];  // dbuf: 2 channels' T each
    __shared__ unsigned int plane[2][2][100];             // [parity][buf] 10r x 40B

    const int tid = threadIdx.x;
    const int bid = blockIdx.x;
    const int quad = bid & 15;               // XCD = bid%8
    const int g = bid >> 4;                  // 0..31
    const int b = g >> 2;
    const int qt = g & 3;                    // image quarter (8 output rows)

    const int p = tid >> 7;                  // channel parity (c mod 2)
    const int lt = tid & 127;
    const int yl = lt >> 4;                  // local row 0..7
    const int x0 = (lt & 15) << 1;           // 2-px strip base col
    const int yg = qt * 8 + yl;

    const char* Tg = (const char*)T + (size_t)quad * 1179648;  // 64*3*256*24
    const float* xb = x + (size_t)b * 65536;

    for (int i = tid; i < 400; i += NT) ((unsigned int*)plane)[i] = 0x80808080u;

    // halo duty (lt<64): hr=0 top (input row qt*8-1), hr=1 bottom; load is
    // ALWAYS issued (clamped row) so every thread has a uniform VMEM count.
    const int hr = (lt >> 5) & 1;
    const int hgrow = qt * 8 + (hr ? 8 : -1);
    const int hvalid = (hgrow >= 0 && hgrow < 32);
    const int hrow = hgrow < 0 ? 0 : (hgrow > 31 ? 31 : hgrow);
    const int hpr = hr ? 9 : 0;
    const int hcol = lt & 31;

    // prologue: pixels for c=p, halo, and stage t=0 into Ts[0]
    float2 xv = *(const float2*)(xb + p * 1024 + yg * 32 + x0);
    float xh = xb[p * 1024 + hrow * 32 + hcol];
    {
        const char* src = Tg + tid * 16;
        char* dst = (char*)Ts[0] + tid * 16;
        #pragma unroll
        for (int k = 0; k < 9; ++k) gll16(src + k * 4096, dst + k * 4096);
    }
    __syncthreads();   // plane init + t0 staging drained (once)

    __half2 z2 = __float2half2_rn(0.f);
    __half2 ah00 = z2, ah01 = z2, ah10 = z2, ah11 = z2;  // [px][o-pair]
    float a32[2][4] = {{0.f, 0.f, 0.f, 0.f}, {0.f, 0.f, 0.f, 0.f}};

    #pragma unroll 1
    for (int t = 0; t < 32; ++t) {
        const int buf = t & 1;
        // A: plane write for c = 2t+p (consumes xv/xh -> compiler waits
        //    vmcnt to retire the 2 pixel loads, leaving t's 9 glls in flight)
        unsigned char* pb = (unsigned char*)plane[p][buf];
        int qa = quantize(xv.x), qb = quantize(xv.y);
        *(unsigned short*)(pb + (yl + 1) * 40 + 4 + x0) =
            (unsigned short)(qa | (qb << 8));
        if (lt < 64 && hvalid) pb[hpr * 40 + 4 + hcol] = (unsigned char)quantize(xh);

        // issue t+1 pixel loads FIRST (so they're older than t+1's glls)
        {
            const int tn = t < 31 ? t + 1 : 31;           // clamped: uniform count
            const int cn = 2 * tn + p;
            xv = *(const float2*)(xb + cn * 1024 + yg * 32 + x0);
            xh = xb[cn * 1024 + hrow * 32 + hcol];
            const char* src = Tg + (size_t)tn * 36864 + tid * 16;
            char* dst = (char*)Ts[buf ^ 1] + tid * 16;
            #pragma unroll
            for (int k = 0; k < 9; ++k) gll16(src + k * 4096, dst + k * 4096);
        }

        // B: tile t's glls retired (11 newest = t+1's stay in flight);
        //    own ds_write done; then barrier -> Ts[buf] + planes visible
        asm volatile("s_waitcnt vmcnt(11) lgkmcnt(0)\n\ts_barrier" ::: "memory");

        // compute channel c = 2t + p from Ts[buf] (v8-proven indexing)
        const unsigned int* pl = plane[p][buf];
        const char* Tp = (const char*)Ts[buf] + p * 18432;
        #pragma unroll
        for (int ky = 0; ky < 3; ++ky) {
            const int pbase = (yl + ky) * 10;
            const int j0 = (x0 + 3) >> 2;
            unsigned int wlo = pl[pbase + j0];
            unsigned int whi = pl[pbase + j0 + 1];
            unsigned long long dv = ((unsigned long long)whi << 32) | wlo;
            unsigned int qbts = (unsigned int)(dv >> (((x0 + 3) & 3) * 8));
            int m0 = (int)(qbts & 255u), m1 = (int)((qbts >> 8) & 255u);
            int m2 = (int)((qbts >> 16) & 255u), m3 = (int)(qbts >> 24);
            const char* Tk = Tp + ky * 6144;
            uint2 A = *(const uint2*)(Tk + m0 * 24);       // px0 k0
            uint2 Bv = *(const uint2*)(Tk + m1 * 24 + 8);  // px0 k1
            uint2 Cv = *(const uint2*)(Tk + m2 * 24 + 16); // px0 k2
            uint2 D = *(const uint2*)(Tk + m1 * 24);       // px1 k0
            uint2 E = *(const uint2*)(Tk + m2 * 24 + 8);   // px1 k1
            uint2 F = *(const uint2*)(Tk + m3 * 24 + 16);  // px1 k2
            ah00 = __hadd2(ah00, *(__half2*)&A.x);  ah01 = __hadd2(ah01, *(__half2*)&A.y);
            ah00 = __hadd2(ah00, *(__half2*)&Bv.x); ah01 = __hadd2(ah01, *(__half2*)&Bv.y);
            ah00 = __hadd2(ah00, *(__half2*)&Cv.x); ah01 = __hadd2(ah01, *(__half2*)&Cv.y);
            ah10 = __hadd2(ah10, *(__half2*)&D.x);  ah11 = __hadd2(ah11, *(__half2*)&D.y);
            ah10 = __hadd2(ah10, *(__half2*)&E.x);  ah11 = __hadd2(ah11, *(__half2*)&E.y);
            ah10 = __hadd2(ah10, *(__half2*)&F.x);  ah11 = __hadd2(ah11, *(__half2*)&F.y);
        }
        if (t & 1) {   // migrate fp16 partials to f32 every 2 channels
            a32[0][0] += __low2float(ah00); a32[0][1] += __high2float(ah00);
            a32[0][2] += __low2float(ah01); a32[0][3] += __high2float(ah01);
            a32[1][0] += __low2float(ah10); a32[1][1] += __high2float(ah10);
            a32[1][2] += __low2float(ah11); a32[1][3] += __high2float(ah11);
            ah00 = z2; ah01 = z2; ah10 = z2; ah11 = z2;
        }

        // D: all compute-t LDS reads done before next iter's writes
        asm volatile("s_waitcnt lgkmcnt(0)\n\ts_barrier" ::: "memory");
    }

    __syncthreads();   // drains the redundant final prefetch -> Ts stable

    // cross-parity reduce via Ts[0] (4KB), then bias + store (v8-proven)
    float* red = (float*)Ts[0];
    if (p) {
        #pragma unroll
        for (int px = 0; px < 2; ++px)
            #pragma unroll
            for (int oo = 0; oo < 4; ++oo)
                red[lt * 8 + px * 4 + oo] = a32[px][oo];
    }
    __syncthreads();
    if (!p) {
        const int o0 = quad * 4;
        #pragma unroll
        for (int oo = 0; oo < 4; ++oo) {
            float bo = bias[o0 + oo];
            float2 r;
            r.x = a32[0][oo] + red[lt * 8 + oo]     + bo;
            r.y = a32[1][oo] + red[lt * 8 + 4 + oo] + bo;
            *(float2*)(out + ((size_t)b * 64 + o0 + oo) * 1024 + yg * 32 + x0) = r;
        }
    }
}

// -------- fallback (proven v1, 98us): used if ws too small ------------------
#define BW1 61
__global__ __launch_bounds__(NT, 2)
void approxconv2d_v1(const float* __restrict__ x,
                     const float* __restrict__ w,
                     const float* __restrict__ bias,
                     const float* __restrict__ lut,
                     float* __restrict__ out)
{
    __shared__ float band[256 * BW1];
    __shared__ unsigned int plane[340];
    __shared__ unsigned char qwrow[576];
    __shared__ int s_min;

    const int tid = threadIdx.x;
    const int bid = blockIdx.x;
    const int b = bid >> 6;
    const int o = bid & 63;

    if (tid == 0) s_min = 255;
    for (int i = tid; i < 340; i += NT) plane[i] = 0x80808080u;
    __syncthreads();

    int lmin = 255;
    for (int i = tid; i < 576; i += NT) {
        int q = quantize(w[o * 576 + i]);
        qwrow[i] = (unsigned char)q;
        lmin = lmin < q ? lmin : q;
    }
    atomicMin(&s_min, lmin);
    __syncthreads();

    int cmin = s_min;
    if (cmin > 256 - BW1) cmin = 256 - BW1;

    for (int i = tid; i < 256 * BW1; i += NT) {
        int qx = i / BW1;
        int cc = i - qx * BW1;
        band[i] = lut[(qx << 8) + cmin + cc];
    }

    const int y  = tid >> 3;
    const int xq = tid & 7;
    const int x0 = xq << 2;

    float acc0 = 0.f, acc1 = 0.f, acc2 = 0.f, acc3 = 0.f;
    const float* xb = x + (size_t)b * 64 * 1024;
    unsigned char* pb = (unsigned char*)plane;

    for (int c = 0; c < 64; ++c) {
        __syncthreads();
        float4 xv = *(const float4*)(xb + c * 1024 + y * 32 + x0);
        int qa = quantize(xv.x), qb = quantize(xv.y);
        int qc = quantize(xv.z), qd = quantize(xv.w);
        int wbase = (y + 1) * 40 + x0 + 1;
        pb[wbase + 0] = (unsigned char)qa;
        pb[wbase + 1] = (unsigned char)qb;
        pb[wbase + 2] = (unsigned char)qc;
        pb[wbase + 3] = (unsigned char)qd;
        __syncthreads();

        const unsigned char* qwp = qwrow + c * 9;
        #pragma unroll
        for (int ky = 0; ky < 3; ++ky) {
            int ro = (y + ky) * 10 + xq;
            unsigned int r0 = plane[ro];
            unsigned int r1 = plane[ro + 1];
            int ee[6];
            ee[0] = (int)(r0 & 255u);
            ee[1] = (int)((r0 >> 8) & 255u);
            ee[2] = (int)((r0 >> 16) & 255u);
            ee[3] = (int)(r0 >> 24);
            ee[4] = (int)(r1 & 255u);
            ee[5] = (int)((r1 >> 8) & 255u);
            int pp[6];
            #pragma unroll
            for (int tt = 0; tt < 6; ++tt) pp[tt] = ee[tt] * BW1;
            #pragma unroll
            for (int kx = 0; kx < 3; ++kx) {
                int cq = (int)qwp[ky * 3 + kx];
                int cc = cq - cmin;
                if ((unsigned)cc < (unsigned)BW1) {
                    acc0 += band[pp[kx + 0] + cc];
                    acc1 += band[pp[kx + 1] + cc];
                    acc2 += band[pp[kx + 2] + cc];
                    acc3 += band[pp[kx + 3] + cc];
                } else {
                    acc0 += lut[(ee[kx + 0] << 8) + cq];
                    acc1 += lut[(ee[kx + 1] << 8) + cq];
                    acc2 += lut[(ee[kx + 2] << 8) + cq];
                    acc3 += lut[(ee[kx + 3] << 8) + cq];
                }
            }
        }
    }

    float bo = bias[o];
    float4 r;
    r.x = acc0 + bo; r.y = acc1 + bo; r.z = acc2 + bo; r.w = acc3 + bo;
    *(float4*)(out + (size_t)bid * 1024 + y * 32 + x0) = r;
}

extern "C" void kernel_launch(void* const* d_in, const int* in_sizes, int n_in,
                              void* d_out, int out_size, void* d_ws, size_t ws_size,
                              hipStream_t stream) {
    const float* x    = (const float*)d_in[0];
    const float* wgt  = (const float*)d_in[1];
    const float* bias = (const float*)d_in[2];
    const float* lut  = (const float*)d_in[3];
    float* out = (float*)d_out;

    const size_t T_BYTES = (size_t)16 * 64 * 3 * 256 * 24;   // 18,874,368
    if (ws_size >= T_BYTES) {
        hipLaunchKernelGGL(build_T4, dim3(512), dim3(NT), 0, stream,
                           wgt, lut, (unsigned int*)d_ws);
        hipLaunchKernelGGL(approx_main, dim3(512), dim3(NT), 0, stream,
                           x, (const unsigned int*)d_ws, bias, out);
    } else {
        hipLaunchKernelGGL(approxconv2d_v1, dim3(512), dim3(NT), 0, stream,
                           x, wgt, bias, lut, out);
    }
}